// Round 9
// baseline (181.476 us; speedup 1.0000x reference)
//
#include <hip/hip_runtime.h>
#include <hip/hip_cooperative_groups.h>

namespace cg = cooperative_groups;

// Problem constants (from reference)
constexpr int NN = 50000;
constexpr int EE = 800000;
constexpr int FF = 64;     // features
constexpr int HH = 256;    // hidden
constexpr int DD = 64;     // out dim
constexpr int GG = 128;    // graphs
constexpr int MAXK = 32;   // max kept/graph (scores sum to 1, >0.05 => <20)
constexpr int MAXQ = 128;  // per-graph surviving-edge queue cap
constexpr int NT = 256;
constexpr float MIN_SCORE = 0.05f;
constexpr float TOL = 1e-7f;
constexpr float EPSV = 1e-14f;

// ====================== fused cooperative kernel ======================
// 4 phases over 3 grid syncs (grid-size agnostic via gridDim.x):
//  A: all blocks  : s = x.pw (streaming dot), zero ecnt
//  B: blocks<GG   : per-graph softmax/threshold/compaction/KL -> out[G+g]
//  C: all blocks  : edge scan w/ LDS kept-table, wave-coop scatter, elist
//  D: blocks<GG   : per-graph GIN MLP tail -> out[g]; block 0 ratio
__global__ __launch_bounds__(NT, 2) void k_fused(
        const float4* __restrict__ x4, const float* __restrict__ x,
        const float4* __restrict__ pw4, const float* __restrict__ na,
        float* __restrict__ s,
        int* __restrict__ kept_i, float* __restrict__ kscore,
        int* __restrict__ kcnt, int* __restrict__ ecnt,
        float* __restrict__ aggc, int* __restrict__ elist,
        const int* __restrict__ ei,
        const float* __restrict__ W1a, const float* __restrict__ b1a,
        const float* __restrict__ W1b, const float* __restrict__ b1b,
        const float* __restrict__ W2a, const float* __restrict__ b2a,
        const float* __restrict__ W2b, const float* __restrict__ b2b,
        const float* __restrict__ Wl, const float* __restrict__ bl,
        float* __restrict__ out) {
    cg::grid_group grid = cg::this_grid();
    int b = blockIdx.x, t = threadIdx.x;
    int nb = gridDim.x;

    __shared__ float red[4];
    __shared__ float sh_smax, sh_esum, sh_kl;
    __shared__ int sh_cnt;
    __shared__ int sh_kcnt[GG];
    __shared__ int sh_kid[GG * MAXK];
    __shared__ float z1[FF], z2[DD], hid[HH], part[4][DD];
    __shared__ int q_cs[MAXQ], q_cd[MAXQ];
    __shared__ int qn, redk[GG];
    __shared__ float gsum_sh;

    // ---------------- phase A: score dot ----------------
    if (b == 0 && t == 0) *ecnt = 0;
    {
        int grp = b * (NT / 16) + (t >> 4);
        int l4 = t & 15;
        float4 pv = pw4[l4];
        for (int r = grp; r < NN; r += nb * (NT / 16)) {
            float4 xv = x4[(size_t)r * 16 + l4];
            float v = xv.x * pv.x + xv.y * pv.y + xv.z * pv.z + xv.w * pv.w;
#pragma unroll
            for (int off = 1; off < 16; off <<= 1) v += __shfl_xor(v, off);
            if (l4 == 0) s[r] = v;
        }
    }
    grid.sync();

    // ---------------- phase B: per-graph pool ----------------
    if (b < GG) {
        int g = b;
        int start = (g * NN + GG - 1) / GG;
        int end   = ((g + 1) * NN + GG - 1) / GG;
        int cnt = end - start;             // 390 or 391
        int wid = t >> 6, lane = t & 63;
        if (t == 0) { sh_kl = 0.f; sh_cnt = 0; }
        float v0 = (t < cnt) ? s[start + t] : -3.4e38f;
        float v1 = (t + NT < cnt) ? s[start + t + NT] : -3.4e38f;
        float m = fmaxf(v0, v1);
#pragma unroll
        for (int off = 32; off; off >>= 1) m = fmaxf(m, __shfl_xor(m, off));
        if (lane == 0) red[wid] = m;
        __syncthreads();
        if (t == 0) sh_smax = fmaxf(fmaxf(red[0], red[1]), fmaxf(red[2], red[3]));
        __syncthreads();
        float smax = sh_smax;

        float e0 = (t < cnt) ? expf(v0 - smax) : 0.f;
        float e1 = (t + NT < cnt) ? expf(v1 - smax) : 0.f;
        float ssum = e0 + e1;
#pragma unroll
        for (int off = 32; off; off >>= 1) ssum += __shfl_xor(ssum, off);
        if (lane == 0) red[wid] = ssum;
        __syncthreads();
        if (t == 0) sh_esum = red[0] + red[1] + red[2] + red[3];
        __syncthreads();
        float esum = sh_esum;

        // scoremax = (max e)/esum = 1/esum exactly (max element: exp(0)=1)
        float thresh = fminf(1.0f / esum - TOL, MIN_SCORE);

        auto handle = [&](int j, float e) {
            if (j >= cnt) return;
            int i = start + j;
            float sc = e / esum;
            if (sc > thresh) {
                int rank = atomicAdd(&sh_cnt, 1);
                if (rank < MAXK) {
                    int cslot = g * MAXK + rank;
                    kept_i[cslot] = i;
                    kscore[cslot] = sc;
                }
                float tt = na[i];
                float tlogt = (tt > 0.f) ? tt * logf(tt) : 0.f;
                atomicAdd(&sh_kl, tlogt - tt * logf(sc + EPSV));
            }
        };
        handle(t, e0);
        handle(t + NT, e1);
        __syncthreads();
        int kc = sh_cnt < MAXK ? sh_cnt : MAXK;
        for (int wdx = t; wdx < kc * DD; wdx += NT)
            aggc[(size_t)g * MAXK * DD + wdx] = 0.f;
        if (t == 0) {
            kcnt[g] = kc;
            out[GG + g] = sh_kl / (float)(sh_cnt > 0 ? sh_cnt : 1);
        }
    }
    grid.sync();

    // ---------------- phase C: edge scan ----------------
    for (int j = t; j < GG; j += NT) sh_kcnt[j] = kcnt[j];
    for (int j = t; j < GG * MAXK; j += NT) sh_kid[j] = kept_i[j];
    __syncthreads();
    {
        int lane = t & 63;
        for (int e = b * NT + t; e < EE; e += nb * NT) {   // wave-uniform trip
            int dn = ei[EE + e];
            int gd = (dn * GG) / NN;       // == batch[dn] (sorted layout)
            int cd = -1;
            int kcd = sh_kcnt[gd];
            for (int j = 0; j < kcd; ++j)
                if (sh_kid[gd * MAXK + j] == dn) { cd = gd * MAXK + j; break; }
            int sn = (cd >= 0) ? ei[e] : 0;

            // wave-cooperative scatter: 64 lanes handle one kept edge together
            unsigned long long hits = __ballot(cd >= 0);
            while (hits) {
                int src_lane = __ffsll(hits) - 1;
                hits &= hits - 1;
                int ecd = __shfl(cd, src_lane);
                int esn = __shfl(sn, src_lane);
                float v = x[(size_t)esn * FF + lane];
                atomicAdd(&aggc[(size_t)ecd * DD + lane], v);
            }

            if (cd >= 0) {
                int gs = (sn * GG) / NN;
                int cs = -1;
                int kcs = sh_kcnt[gs];
                for (int j = 0; j < kcs; ++j)
                    if (sh_kid[gs * MAXK + j] == sn) { cs = gs * MAXK + j; break; }
                if (cs >= 0) {
                    int j = atomicAdd(ecnt, 1);
                    elist[2 * j] = cs;
                    elist[2 * j + 1] = cd;
                }
            }
        }
    }
    grid.sync();

    // ---------------- phase D: MLP tail ----------------
    if (b >= GG) return;
    {
        int g = b;
        if (g == 0) {       // ratio
            if (t < GG) redk[t] = kcnt[t];
            __syncthreads();
            if (t == 0) {
                int ssm = 0;
#pragma unroll
                for (int j = 0; j < GG; ++j) ssm += redk[j];
                out[2 * GG] = (float)ssm / (float)NN;
            }
        }

        int kc = kcnt[g];
        int lo = g * MAXK, hi = lo + kc;
        if (t == 0) { qn = 0; gsum_sh = 0.f; }
        __syncthreads();

        int en = *ecnt;
        for (int j = t; j < en; j += NT) {
            int cd = elist[2 * j + 1];
            if (cd >= lo && cd < hi) {
                int pos = atomicAdd(&qn, 1);
                if (pos < MAXQ) { q_cs[pos] = elist[2 * j]; q_cd[pos] = cd; }
            }
        }
        __syncthreads();
        int nq = qn < MAXQ ? qn : MAXQ;

        int d = t & 63, qw = t >> 6;

        auto mlp1_accum = [&](int cs) {
            __syncthreads();
            if (t < FF)
                z1[t] = x[(size_t)sh_kid[cs] * FF + t] + aggc[(size_t)cs * DD + t];
            __syncthreads();
            float a = b1a[t];
#pragma unroll 16
            for (int f = 0; f < FF; ++f) a += z1[f] * W1a[f * HH + t];
            hid[t] = fmaxf(a, 0.f);
            __syncthreads();
            float acc = 0.f;
#pragma unroll 16
            for (int h = 0; h < HH / 4; ++h)
                acc += hid[qw * 64 + h] * W1b[(qw * 64 + h) * DD + d];
            part[qw][d] = acc;
            __syncthreads();
            if (t < DD)
                z2[t] += fmaxf(b1b[t] + part[0][t] + part[1][t] + part[2][t] +
                               part[3][t], 0.f) * kscore[cs];
        };

        for (int r = 0; r < kc; ++r) {
            int c = lo + r;
            if (t < DD) z2[t] = 0.f;
            mlp1_accum(c);                    // own node
            for (int j = 0; j < nq; ++j)      // LDS-uniform queue, ~0-2 entries
                if (q_cd[j] == c) mlp1_accum(q_cs[j]);
            __syncthreads();

            float a = b2a[t];
#pragma unroll 16
            for (int f = 0; f < DD; ++f) a += z2[f] * W2a[f * HH + t];
            hid[t] = fmaxf(a, 0.f);
            __syncthreads();
            float acc = 0.f;
#pragma unroll 16
            for (int h = 0; h < HH / 4; ++h)
                acc += hid[qw * 64 + h] * W2b[(qw * 64 + h) * DD + d];
            part[qw][d] = acc;
            __syncthreads();
            if (t < DD) {
                float v = fmaxf(b2b[t] + part[0][t] + part[1][t] + part[2][t] +
                                part[3][t], 0.f);
                float p = v * Wl[t];
#pragma unroll
                for (int off = 1; off < 64; off <<= 1) p += __shfl_xor(p, off);
                if (t == 0) gsum_sh += p;
            }
            __syncthreads();                  // before next slot reuses z2/hid
        }
        if (t == 0) out[g] = gsum_sh + bl[0];
    }
}

// ====================== fallback: proven R7 3-kernel path ======================

__global__ __launch_bounds__(1024) void k_pool(
        const float4* __restrict__ x4, const float4* __restrict__ pw4,
        const float* __restrict__ na,
        int* __restrict__ kept_i, float* __restrict__ kscore,
        int* __restrict__ kcnt, int* __restrict__ ecnt,
        float* __restrict__ aggc, float* __restrict__ out) {
    int g = blockIdx.x;
    int start = (g * NN + GG - 1) / GG;
    int end   = ((g + 1) * NN + GG - 1) / GG;
    int cnt = end - start;
    int t = threadIdx.x;
    int wid = t >> 6, lane = t & 63;
    __shared__ float ev[400];
    __shared__ float red[16];
    __shared__ float sh_smax, sh_esum, sh_kl;
    __shared__ int sh_cnt;

    if (g == 0 && t == 0) *ecnt = 0;
    if (t == 0) { sh_kl = 0.f; sh_cnt = 0; }

    int grp = t >> 4, l4 = t & 15;
    float4 pv = pw4[l4];
    for (int r = grp; r < cnt; r += 64) {
        float4 xv = x4[(size_t)(start + r) * 16 + l4];
        float v = xv.x * pv.x + xv.y * pv.y + xv.z * pv.z + xv.w * pv.w;
#pragma unroll
        for (int off = 1; off < 16; off <<= 1) v += __shfl_xor(v, off);
        if (l4 == 0) ev[r] = v;
    }
    __syncthreads();

    float m = (t < cnt) ? ev[t] : -3.4e38f;
#pragma unroll
    for (int off = 32; off; off >>= 1) m = fmaxf(m, __shfl_xor(m, off));
    if (lane == 0) red[wid] = m;
    __syncthreads();
    if (t == 0) {
        float mm = red[0];
#pragma unroll
        for (int j = 1; j < 16; ++j) mm = fmaxf(mm, red[j]);
        sh_smax = mm;
    }
    __syncthreads();
    float smax = sh_smax;

    float e = (t < cnt) ? expf(ev[t] - smax) : 0.f;
    float ssum = e;
#pragma unroll
    for (int off = 32; off; off >>= 1) ssum += __shfl_xor(ssum, off);
    if (lane == 0) red[wid] = ssum;
    __syncthreads();
    if (t == 0) {
        float s16 = red[0];
#pragma unroll
        for (int j = 1; j < 16; ++j) s16 += red[j];
        sh_esum = s16;
    }
    __syncthreads();
    float esum = sh_esum;

    float thresh = fminf(1.0f / esum - TOL, MIN_SCORE);

    if (t < cnt) {
        int i = start + t;
        float sc = e / esum;
        if (sc > thresh) {
            int rank = atomicAdd(&sh_cnt, 1);
            if (rank < MAXK) {
                int cslot = g * MAXK + rank;
                kept_i[cslot] = i;
                kscore[cslot] = sc;
            }
            float tt = na[i];
            float tlogt = (tt > 0.f) ? tt * logf(tt) : 0.f;
            atomicAdd(&sh_kl, tlogt - tt * logf(sc + EPSV));
        }
    }
    __syncthreads();
    int kc = sh_cnt < MAXK ? sh_cnt : MAXK;
    for (int wdx = t; wdx < kc * DD; wdx += 1024)
        aggc[(size_t)g * MAXK * DD + wdx] = 0.f;
    if (t == 0) {
        kcnt[g] = kc;
        out[GG + g] = sh_kl / (float)(sh_cnt > 0 ? sh_cnt : 1);
    }
}

__global__ __launch_bounds__(256) void k_edge(
        const int* __restrict__ ei, const float* __restrict__ x,
        const int* __restrict__ kept_i, const int* __restrict__ kcnt,
        float* __restrict__ aggc, int* __restrict__ elist,
        int* __restrict__ ecnt) {
    __shared__ int sh_kcnt[GG];
    __shared__ int sh_kid[GG * MAXK];
    int t = threadIdx.x;
    for (int j = t; j < GG; j += 256) sh_kcnt[j] = kcnt[j];
    for (int j = t; j < GG * MAXK; j += 256) sh_kid[j] = kept_i[j];
    __syncthreads();

    int e = blockIdx.x * 256 + t;
    int lane = t & 63;
    int dn = ei[EE + e];
    int gd = (dn * GG) / NN;
    int cd = -1;
    int kcd = sh_kcnt[gd];
    for (int j = 0; j < kcd; ++j)
        if (sh_kid[gd * MAXK + j] == dn) { cd = gd * MAXK + j; break; }

    int sn = (cd >= 0) ? ei[e] : 0;

    unsigned long long hits = __ballot(cd >= 0);
    while (hits) {
        int src_lane = __ffsll(hits) - 1;
        hits &= hits - 1;
        int ecd = __shfl(cd, src_lane);
        int esn = __shfl(sn, src_lane);
        float v = x[(size_t)esn * FF + lane];
        atomicAdd(&aggc[(size_t)ecd * DD + lane], v);
    }

    if (cd >= 0) {
        int gs = (sn * GG) / NN;
        int cs = -1;
        int kcs = sh_kcnt[gs];
        for (int j = 0; j < kcs; ++j)
            if (sh_kid[gs * MAXK + j] == sn) { cs = gs * MAXK + j; break; }
        if (cs >= 0) {
            int j = atomicAdd(ecnt, 1);
            elist[2 * j] = cs;
            elist[2 * j + 1] = cd;
        }
    }
}

__global__ __launch_bounds__(256) void k_tail2(
        const float* __restrict__ x, const int* __restrict__ kept_i,
        const float* __restrict__ kscore, const int* __restrict__ kcnt,
        const int* __restrict__ elist, const int* __restrict__ ecnt,
        const float* __restrict__ aggc,
        const float* __restrict__ W1a, const float* __restrict__ b1a,
        const float* __restrict__ W1b, const float* __restrict__ b1b,
        const float* __restrict__ W2a, const float* __restrict__ b2a,
        const float* __restrict__ W2b, const float* __restrict__ b2b,
        const float* __restrict__ Wl, const float* __restrict__ bl,
        float* __restrict__ out) {
    int g = blockIdx.x;
    int t = threadIdx.x;
    __shared__ float z1[FF], z2[DD], hid[HH], part[4][DD];
    __shared__ int q_cs[MAXQ], q_cd[MAXQ];
    __shared__ int qn, redk[GG];
    __shared__ float gsum_sh;

    if (g == 0) {
        if (t < GG) redk[t] = kcnt[t];
        __syncthreads();
        if (t == 0) {
            int s = 0;
#pragma unroll
            for (int j = 0; j < GG; ++j) s += redk[j];
            out[2 * GG] = (float)s / (float)NN;
        }
    }

    int kc = kcnt[g];
    int lo = g * MAXK, hi = lo + kc;
    if (t == 0) { qn = 0; gsum_sh = 0.f; }
    __syncthreads();

    int en = *ecnt;
    for (int j = t; j < en; j += 256) {
        int cd = elist[2 * j + 1];
        if (cd >= lo && cd < hi) {
            int pos = atomicAdd(&qn, 1);
            if (pos < MAXQ) { q_cs[pos] = elist[2 * j]; q_cd[pos] = cd; }
        }
    }
    __syncthreads();
    int nq = qn < MAXQ ? qn : MAXQ;

    int d = t & 63, qw = t >> 6;

    auto mlp1_accum = [&](int cs) {
        __syncthreads();
        if (t < FF) z1[t] = x[(size_t)kept_i[cs] * FF + t] + aggc[(size_t)cs * DD + t];
        __syncthreads();
        float a = b1a[t];
#pragma unroll 16
        for (int f = 0; f < FF; ++f) a += z1[f] * W1a[f * HH + t];
        hid[t] = fmaxf(a, 0.f);
        __syncthreads();
        float acc = 0.f;
#pragma unroll 16
        for (int h = 0; h < HH / 4; ++h)
            acc += hid[qw * 64 + h] * W1b[(qw * 64 + h) * DD + d];
        part[qw][d] = acc;
        __syncthreads();
        if (t < DD)
            z2[t] += fmaxf(b1b[t] + part[0][t] + part[1][t] + part[2][t] + part[3][t],
                           0.f) * kscore[cs];
    };

    for (int r = 0; r < kc; ++r) {
        int c = lo + r;
        if (t < DD) z2[t] = 0.f;
        mlp1_accum(c);
        for (int j = 0; j < nq; ++j)
            if (q_cd[j] == c) mlp1_accum(q_cs[j]);
        __syncthreads();

        float a = b2a[t];
#pragma unroll 16
        for (int f = 0; f < DD; ++f) a += z2[f] * W2a[f * HH + t];
        hid[t] = fmaxf(a, 0.f);
        __syncthreads();
        float acc = 0.f;
#pragma unroll 16
        for (int h = 0; h < HH / 4; ++h)
            acc += hid[qw * 64 + h] * W2b[(qw * 64 + h) * DD + d];
        part[qw][d] = acc;
        __syncthreads();
        if (t < DD) {
            float v = fmaxf(b2b[t] + part[0][t] + part[1][t] + part[2][t] + part[3][t],
                            0.f);
            float p = v * Wl[t];
#pragma unroll
            for (int off = 1; off < 64; off <<= 1) p += __shfl_xor(p, off);
            if (t == 0) gsum_sh += p;
        }
        __syncthreads();
    }
    if (t == 0) out[g] = gsum_sh + bl[0];
}

extern "C" void kernel_launch(void* const* d_in, const int* in_sizes, int n_in,
                              void* d_out, int out_size, void* d_ws, size_t ws_size,
                              hipStream_t stream) {
    const float* x   = (const float*)d_in[0];
    const float* na  = (const float*)d_in[1];
    const float* W1a = (const float*)d_in[2];
    const float* b1a = (const float*)d_in[3];
    const float* W1b = (const float*)d_in[4];
    const float* b1b = (const float*)d_in[5];
    const float* pw  = (const float*)d_in[6];
    const float* W2a = (const float*)d_in[7];
    const float* b2a = (const float*)d_in[8];
    const float* W2b = (const float*)d_in[9];
    const float* b2b = (const float*)d_in[10];
    const float* Wl  = (const float*)d_in[11];
    const float* bl  = (const float*)d_in[12];
    const int* ei    = (const int*)d_in[13];
    float* out = (float*)d_out;

    // ---- workspace layout (256B aligned blocks); no pre-zeroing needed ----
    char* w = (char*)d_ws;
    auto alloc = [&](size_t bytes) -> void* {
        void* p = (void*)w;
        w += (bytes + 255) & ~(size_t)255;
        return p;
    };
    int*   ecnt    = (int*)alloc(4);                          // zeroed in-kernel
    int*   kcnt    = (int*)alloc(GG * 4);
    int*   kept_i  = (int*)alloc((size_t)GG * MAXK * 4);
    float* kscore  = (float*)alloc((size_t)GG * MAXK * 4);
    float* s       = (float*)alloc((size_t)NN * 4);
    float* aggc    = (float*)alloc((size_t)GG * MAXK * DD * 4);
    int*   elist   = (int*)alloc((size_t)2 * EE * 4);
    (void)ws_size; (void)in_sizes; (void)n_in; (void)out_size;

    const float4* x4v = (const float4*)x;
    const float4* pw4v = (const float4*)pw;
    void* args[] = {
        (void*)&x4v, (void*)&x, (void*)&pw4v, (void*)&na, (void*)&s,
        (void*)&kept_i, (void*)&kscore, (void*)&kcnt, (void*)&ecnt,
        (void*)&aggc, (void*)&elist, (void*)&ei,
        (void*)&W1a, (void*)&b1a, (void*)&W1b, (void*)&b1b,
        (void*)&W2a, (void*)&b2a, (void*)&W2b, (void*)&b2b,
        (void*)&Wl, (void*)&bl, (void*)&out,
    };

    // Try cooperative fusion at decreasing widths; fall back to the proven
    // 3-kernel path if the runtime rejects cooperative launch entirely.
    hipError_t err = hipErrorUnknown;
    for (int nb : {512, 256, 128}) {
        err = hipLaunchCooperativeKernel((const void*)k_fused, dim3(nb),
                                         dim3(NT), args, 0, stream);
        if (err == hipSuccess) break;
        (void)hipGetLastError();   // clear sticky error state
    }
    if (err == hipSuccess) return;

    k_pool<<<GG, 1024, 0, stream>>>((const float4*)x, (const float4*)pw, na,
                                    kept_i, kscore, kcnt, ecnt, aggc, out);
    k_edge<<<EE / 256, 256, 0, stream>>>(ei, x, kept_i, kcnt, aggc, elist, ecnt);
    k_tail2<<<GG, 256, 0, stream>>>(x, kept_i, kscore, kcnt, elist, ecnt,
                                    aggc, W1a, b1a, W1b, b1b,
                                    W2a, b2a, W2b, b2b, Wl, bl, out);
}

// Round 10
// 27.848 us; speedup vs baseline: 6.5168x; 6.5168x over previous
//
#include <hip/hip_runtime.h>

// Problem constants (from reference)
constexpr int NN = 50000;
constexpr int EE = 800000;
constexpr int FF = 64;     // features
constexpr int HH = 256;    // hidden
constexpr int DD = 64;     // out dim
constexpr int GG = 128;    // graphs
constexpr int MAXK = 32;   // max kept/graph (scores sum to 1, >0.05 => <20)
constexpr int MAXQ = 128;  // per-graph surviving-edge queue cap
constexpr int WPG = 16;    // bitmask words per graph (512 bits >= 391 nodes)
constexpr float MIN_SCORE = 0.05f;
constexpr float TOL = 1e-7f;
constexpr float EPSV = 1e-14f;

// K1: one block per graph (nodes [ceil(gN/G), ceil((g+1)N/G)) -- contiguous).
// 1024 threads: s = x.pw for own nodes, softmax, threshold, slot compaction,
// keep-BITMASK (graph-padded, 16 words/graph), KL. Writes out[G+g], zeroes
// own agg rows, zeroes ecnt.
__global__ __launch_bounds__(1024) void k_pool(
        const float4* __restrict__ x4, const float4* __restrict__ pw4,
        const float* __restrict__ na,
        int* __restrict__ kept_i, float* __restrict__ kscore,
        int* __restrict__ kcnt, unsigned* __restrict__ kmask,
        int* __restrict__ ecnt, float* __restrict__ aggc,
        float* __restrict__ out) {
    int g = blockIdx.x;
    int start = (g * NN + GG - 1) / GG;
    int end   = ((g + 1) * NN + GG - 1) / GG;
    int cnt = end - start;                 // 390 or 391
    int t = threadIdx.x;
    int wid = t >> 6, lane = t & 63;
    __shared__ float ev[400];
    __shared__ float red[16];
    __shared__ float sh_smax, sh_esum, sh_kl;
    __shared__ int sh_cnt;
    __shared__ unsigned shmask[WPG];

    if (g == 0 && t == 0) *ecnt = 0;
    if (t == 0) { sh_kl = 0.f; sh_cnt = 0; }
    if (t < WPG) shmask[t] = 0u;

    // s = x . pw : 16 lanes per row (float4 each), 64 row-groups over 1024 thr
    int grp = t >> 4, l4 = t & 15;
    float4 pv = pw4[l4];
    for (int r = grp; r < cnt; r += 64) {
        float4 xv = x4[(size_t)(start + r) * 16 + l4];
        float v = xv.x * pv.x + xv.y * pv.y + xv.z * pv.z + xv.w * pv.w;
#pragma unroll
        for (int off = 1; off < 16; off <<= 1) v += __shfl_xor(v, off);
        if (l4 == 0) ev[r] = v;
    }
    __syncthreads();

    // block max
    float m = (t < cnt) ? ev[t] : -3.4e38f;
#pragma unroll
    for (int off = 32; off; off >>= 1) m = fmaxf(m, __shfl_xor(m, off));
    if (lane == 0) red[wid] = m;
    __syncthreads();
    if (t == 0) {
        float mm = red[0];
#pragma unroll
        for (int j = 1; j < 16; ++j) mm = fmaxf(mm, red[j]);
        sh_smax = mm;
    }
    __syncthreads();
    float smax = sh_smax;

    // exp + block sum
    float e = (t < cnt) ? expf(ev[t] - smax) : 0.f;
    float ssum = e;
#pragma unroll
    for (int off = 32; off; off >>= 1) ssum += __shfl_xor(ssum, off);
    if (lane == 0) red[wid] = ssum;
    __syncthreads();
    if (t == 0) {
        float s16 = red[0];
#pragma unroll
        for (int j = 1; j < 16; ++j) s16 += red[j];
        sh_esum = s16;
    }
    __syncthreads();
    float esum = sh_esum;

    // scoremax = (max e)/esum = 1/esum exactly (max element: exp(0)=1)
    float thresh = fminf(1.0f / esum - TOL, MIN_SCORE);

    // mask + slot compaction + bitmask + KL
    if (t < cnt) {
        int i = start + t;
        float sc = e / esum;
        if (sc > thresh) {
            int rank = atomicAdd(&sh_cnt, 1);
            if (rank < MAXK) {
                int cslot = g * MAXK + rank;
                kept_i[cslot] = i;
                kscore[cslot] = sc;
                atomicOr(&shmask[t >> 5], 1u << (t & 31));  // local idx = t
            }
            float tt = na[i];
            float tlogt = (tt > 0.f) ? tt * logf(tt) : 0.f;
            atomicAdd(&sh_kl, tlogt - tt * logf(sc + EPSV));
        }
    }
    __syncthreads();
    int kc = sh_cnt < MAXK ? sh_cnt : MAXK;
    if (t < WPG) kmask[g * WPG + t] = shmask[t];
    // zero agg rows for own kept slots (contiguous region of kc*DD floats)
    for (int wdx = t; wdx < kc * DD; wdx += 1024)
        aggc[(size_t)g * MAXK * DD + wdx] = 0.f;
    if (t == 0) {
        kcnt[g] = kc;
        out[GG + g] = sh_kl / (float)(sh_cnt > 0 ? sh_cnt : 1);
    }
}

// K2: edge scan via L1-resident keep bitmask (8KB total) — no LDS staging,
// no LDS search. 4 edges/thread via int4 dst loads. For kept-dst edges:
// wave-cooperative scatter of x[src] into aggc[slot]; both-kept -> elist.
__global__ __launch_bounds__(256) void k_edge(
        const int* __restrict__ ei, const float* __restrict__ x,
        const int* __restrict__ kept_i, const int* __restrict__ kcnt,
        const unsigned* __restrict__ kmask,
        float* __restrict__ aggc, int* __restrict__ elist,
        int* __restrict__ ecnt) {
    int t = threadIdx.x;
    int lane = t & 63;
    int e4 = blockIdx.x * 256 + t;
    bool valid = e4 < EE / 4;
    int4 dv = {0, 0, 0, 0};
    if (valid) dv = ((const int4*)(ei + EE))[e4];
    int ds[4] = {dv.x, dv.y, dv.z, dv.w};

    // membership: graph-padded bitmask, local index = node - graph_start
    auto keep_slot = [&](int node) -> int {   // -1 if not kept
        int gph = (node * GG) / NN;           // == batch[node] (sorted layout)
        int st = (gph * NN + GG - 1) / GG;
        int local = node - st;
        unsigned wm = kmask[gph * WPG + (local >> 5)];
        if (!((wm >> (local & 31)) & 1u)) return -1;
        int kcd = kcnt[gph];                  // rare path (~2k edges)
        for (int j = 0; j < kcd; ++j)
            if (kept_i[gph * MAXK + j] == node) return gph * MAXK + j;
        return -1;
    };

#pragma unroll
    for (int k = 0; k < 4; ++k) {
        int cd = -1;
        if (valid) cd = keep_slot(ds[k]);
        int sn = (cd >= 0) ? ei[e4 * 4 + k] : 0;

        // wave-cooperative scatter: 64 lanes handle one kept edge together
        unsigned long long hits = __ballot(cd >= 0);
        while (hits) {
            int src_lane = __ffsll(hits) - 1;
            hits &= hits - 1;
            int ecd = __shfl(cd, src_lane);
            int esn = __shfl(sn, src_lane);
            float v = x[(size_t)esn * FF + lane];
            atomicAdd(&aggc[(size_t)ecd * DD + lane], v);
        }

        if (cd >= 0) {
            int cs = keep_slot(sn);
            if (cs >= 0) {
                int j = atomicAdd(ecnt, 1);
                elist[2 * j] = cs;
                elist[2 * j + 1] = cd;
            }
        }
    }
}

// K3: one block PER GRAPH (grid=128). Per kept slot: MLP1 (+ MLP1 of
// surviving-edge srcs via LDS queue), MLP2, dot with Wl; block-owned
// accumulation -> out[g] (no atomics). Block 0 computes ratio.
__global__ __launch_bounds__(256) void k_tail2(
        const float* __restrict__ x, const int* __restrict__ kept_i,
        const float* __restrict__ kscore, const int* __restrict__ kcnt,
        const int* __restrict__ elist, const int* __restrict__ ecnt,
        const float* __restrict__ aggc,
        const float* __restrict__ W1a, const float* __restrict__ b1a,
        const float* __restrict__ W1b, const float* __restrict__ b1b,
        const float* __restrict__ W2a, const float* __restrict__ b2a,
        const float* __restrict__ W2b, const float* __restrict__ b2b,
        const float* __restrict__ Wl, const float* __restrict__ bl,
        float* __restrict__ out) {
    int g = blockIdx.x;
    int t = threadIdx.x;
    __shared__ float z1[FF], z2[DD], hid[HH], part[4][DD];
    __shared__ int q_cs[MAXQ], q_cd[MAXQ];
    __shared__ int qn, redk[GG];
    __shared__ float gsum_sh;

    if (g == 0) {           // ratio
        if (t < GG) redk[t] = kcnt[t];
        __syncthreads();
        if (t == 0) {
            int s = 0;
#pragma unroll
            for (int j = 0; j < GG; ++j) s += redk[j];
            out[2 * GG] = (float)s / (float)NN;
        }
    }

    int kc = kcnt[g];
    int lo = g * MAXK, hi = lo + kc;
    if (t == 0) { qn = 0; gsum_sh = 0.f; }
    __syncthreads();

    // cooperative scan of surviving-edge list for edges into MY slots
    int en = *ecnt;
    for (int j = t; j < en; j += 256) {
        int cd = elist[2 * j + 1];
        if (cd >= lo && cd < hi) {
            int pos = atomicAdd(&qn, 1);
            if (pos < MAXQ) { q_cs[pos] = elist[2 * j]; q_cd[pos] = cd; }
        }
    }
    __syncthreads();
    int nq = qn < MAXQ ? qn : MAXQ;

    int d = t & 63, qw = t >> 6;

    // MLP1 of slot cs, accumulate result*score into z2
    auto mlp1_accum = [&](int cs) {
        __syncthreads();
        if (t < FF) z1[t] = x[(size_t)kept_i[cs] * FF + t] + aggc[(size_t)cs * DD + t];
        __syncthreads();
        float a = b1a[t];
#pragma unroll 16
        for (int f = 0; f < FF; ++f) a += z1[f] * W1a[f * HH + t];
        hid[t] = fmaxf(a, 0.f);
        __syncthreads();
        float acc = 0.f;
#pragma unroll 16
        for (int h = 0; h < HH / 4; ++h)
            acc += hid[qw * 64 + h] * W1b[(qw * 64 + h) * DD + d];
        part[qw][d] = acc;
        __syncthreads();
        if (t < DD)
            z2[t] += fmaxf(b1b[t] + part[0][t] + part[1][t] + part[2][t] + part[3][t],
                           0.f) * kscore[cs];
    };

    for (int r = 0; r < kc; ++r) {
        int c = lo + r;
        if (t < DD) z2[t] = 0.f;
        mlp1_accum(c);                    // own node
        for (int j = 0; j < nq; ++j)      // LDS-uniform queue, ~0-2 entries
            if (q_cd[j] == c) mlp1_accum(q_cs[j]);
        __syncthreads();

        // MLP2
        float a = b2a[t];
#pragma unroll 16
        for (int f = 0; f < DD; ++f) a += z2[f] * W2a[f * HH + t];
        hid[t] = fmaxf(a, 0.f);
        __syncthreads();
        float acc = 0.f;
#pragma unroll 16
        for (int h = 0; h < HH / 4; ++h)
            acc += hid[qw * 64 + h] * W2b[(qw * 64 + h) * DD + d];
        part[qw][d] = acc;
        __syncthreads();
        if (t < DD) {
            float v = fmaxf(b2b[t] + part[0][t] + part[1][t] + part[2][t] + part[3][t],
                            0.f);
            float p = v * Wl[t];
#pragma unroll
            for (int off = 1; off < 64; off <<= 1) p += __shfl_xor(p, off);
            if (t == 0) gsum_sh += p;
        }
        __syncthreads();                  // before next slot reuses z2/hid
    }
    if (t == 0) out[g] = gsum_sh + bl[0];
}

extern "C" void kernel_launch(void* const* d_in, const int* in_sizes, int n_in,
                              void* d_out, int out_size, void* d_ws, size_t ws_size,
                              hipStream_t stream) {
    const float* x   = (const float*)d_in[0];
    const float* na  = (const float*)d_in[1];
    const float* W1a = (const float*)d_in[2];
    const float* b1a = (const float*)d_in[3];
    const float* W1b = (const float*)d_in[4];
    const float* b1b = (const float*)d_in[5];
    const float* pw  = (const float*)d_in[6];
    const float* W2a = (const float*)d_in[7];
    const float* b2a = (const float*)d_in[8];
    const float* W2b = (const float*)d_in[9];
    const float* b2b = (const float*)d_in[10];
    const float* Wl  = (const float*)d_in[11];
    const float* bl  = (const float*)d_in[12];
    const int* ei    = (const int*)d_in[13];
    float* out = (float*)d_out;

    // ---- workspace layout (256B aligned blocks); no pre-zeroing needed ----
    char* w = (char*)d_ws;
    auto alloc = [&](size_t bytes) -> void* {
        void* p = (void*)w;
        w += (bytes + 255) & ~(size_t)255;
        return p;
    };
    int*      ecnt   = (int*)alloc(4);                          // zeroed by k_pool
    int*      kcnt   = (int*)alloc(GG * 4);                     // written by k_pool
    int*      kept_i = (int*)alloc((size_t)GG * MAXK * 4);      // valid slots only
    float*    kscore = (float*)alloc((size_t)GG * MAXK * 4);
    unsigned* kmask  = (unsigned*)alloc((size_t)GG * WPG * 4);  // written by k_pool
    float*    aggc   = (float*)alloc((size_t)GG * MAXK * DD * 4); // zeroed by k_pool
    int*      elist  = (int*)alloc((size_t)2 * EE * 4);
    (void)ws_size; (void)in_sizes; (void)n_in; (void)out_size;

    k_pool<<<GG, 1024, 0, stream>>>((const float4*)x, (const float4*)pw, na,
                                    kept_i, kscore, kcnt, kmask, ecnt, aggc, out);
    k_edge<<<(EE / 4 + 255) / 256, 256, 0, stream>>>(ei, x, kept_i, kcnt, kmask,
                                                     aggc, elist, ecnt);
    k_tail2<<<GG, 256, 0, stream>>>(x, kept_i, kscore, kcnt, elist, ecnt,
                                    aggc, W1a, b1a, W1b, b1b,
                                    W2a, b2a, W2b, b2b, Wl, bl, out);
}